// Round 5
// baseline (133.746 us; speedup 1.0000x reference)
//
#include <hip/hip_runtime.h>
#include <math.h>

#define NB 1024
#define NR 512
#define ND 256
#define XS_STRIDE 260   // multiple of 4 -> 16B-aligned rows for ds_read_b128; 260%32=4 -> b128 reads at the 8-cyc floor

typedef float v4f __attribute__((ext_vector_type(4)));

constexpr float kBETA  = 6.0f;
constexpr float kLOG2E = 1.4426950408889634f;

#if __has_builtin(__builtin_amdgcn_exp2f)
__device__ __forceinline__ float fast_exp2(float x) { return __builtin_amdgcn_exp2f(x); }
#else
__device__ __forceinline__ float fast_exp2(float x) { return exp2f(x); }
#endif
#if __has_builtin(__builtin_amdgcn_rcpf)
__device__ __forceinline__ float fast_rcp(float x) { return __builtin_amdgcn_rcpf(x); }
#else
__device__ __forceinline__ float fast_rcp(float x) { return 1.0f / x; }
#endif

__device__ __forceinline__ float fast_sigmoid(float a) {   // 1/(1+e^-a)
    return fast_rcp(1.0f + fast_exp2(-a * kLOG2E));
}
__device__ __forceinline__ float fast_tanh(float a) {      // 1 - 2/(1+e^{2a})
    return 1.0f - 2.0f * fast_rcp(1.0f + fast_exp2(a * (2.0f * kLOG2E)));
}

// Prep: P4[r*ND+d] = {E, K, nmK, meh} with
//   E   = exp2(-s*t_high)            (b = Xe*E, Xe = exp2(s*x): separable exp)
//   K   = exp2(-s*width)
//   nmK = -mel*K                      (partial fractions: mel*b/(b+K) = mel - mel*K/(b+K))
//   meh = sig(mask)*tanh(e_high), mel likewise with e_low
// baseR[r] = sum_d (meh - mel)   (mel constant folded out of the fraction)
__global__ __launch_bounds__(256) void prep_kernel(
    const float* __restrict__ center, const float* __restrict__ log_width,
    const float* __restrict__ e_low, const float* __restrict__ e_high,
    const float* __restrict__ mask, const float* __restrict__ log_kappa,
    const float* __restrict__ head_b,
    float4* __restrict__ P4, float* __restrict__ baseR, float* __restrict__ y)
{
    const int r = blockIdx.x;
    const int d = threadIdx.x;
    const int idx = r * ND + d;

    const float kappa = fminf(fmaxf(fast_exp2(log_kappa[0] * kLOG2E), 0.5f), 50.0f);
    const float s = kappa * kLOG2E;

    const float wdt = fminf(fmaxf(fast_exp2(log_width[idx] * kLOG2E), 0.001f), 50.0f);
    const float th  = center[idx] + 0.5f * wdt;
    const float E   = fast_exp2(-s * th);
    const float K   = fmaxf(fast_exp2(-s * wdt), 1e-30f);   // floor: keeps den > 0
    const float m   = fast_sigmoid(mask[idx]);
    const float mel = m * fast_tanh(e_low[idx]);
    const float meh = m * fast_tanh(e_high[idx]);

    float4 p; p.x = E; p.y = K; p.z = -mel * K; p.w = meh;
    P4[idx] = p;

    float v = meh - mel;
    #pragma unroll
    for (int off = 32; off > 0; off >>= 1) v += __shfl_down(v, off, 64);
    __shared__ float red[4];
    if ((d & 63) == 0) red[d >> 6] = v;
    __syncthreads();
    if (d == 0) baseR[r] = red[0] + red[1] + red[2] + red[3];

    const int gid = blockIdx.x * 256 + threadIdx.x;
    if (gid < NB) y[gid] = head_b[0];
}

// Per element (7 VALU + 1 rcp, no exp):
//   b = Xe*E; u = b+1; v = b+K; acc += (nmK*u + meh*v) / (u*v)
//   evidence = baseR - 2*acc
__device__ __forceinline__ void elemstep(const float X, const float4 p, float& acc)
{
    const float b   = X * p.x;
    const float u   = b + 1.0f;
    const float v   = b + p.y;
    const float num = fmaf(p.z, u, p.w * v);
    const float den = u * v;
    acc = fmaf(num, fast_rcp(den), acc);
}

// Main: 1024 threads = 16 waves; wave w -> r = blockIdx.y*16 + w; lane = b.
// x: LDS tile (Xe = exp2(s*x)), ds_read_b128 (pure-DS lgkmcnt, in-order).
// P: wave-uniform-address global_load_dwordx4 (vmcnt domain, broadcast line,
//    deep pipelining) -- deliberately NOT s_load: mixing SMEM into lgkmcnt
//    forces lgkmcnt(0) drains and thrashes the scalar cache.
__global__ __launch_bounds__(1024, 8) void evid_kernel(
    const float* __restrict__ x, const float* __restrict__ log_kappa,
    const float* __restrict__ t_arr, const float* __restrict__ head_w,
    const float4* __restrict__ P4, const float* __restrict__ baseR,
    float* __restrict__ y)
{
    __shared__ float xs[64 * XS_STRIDE];

    const int tid = threadIdx.x;
    const int b0 = blockIdx.x * 64;

    const float kappa = fminf(fmaxf(fast_exp2(log_kappa[0] * kLOG2E), 0.5f), 50.0f);
    const float s = kappa * kLOG2E;

    // Stage Xe = exp2(s*x): coalesced float4 global reads, ds_write_b128.
    const float4* xg = (const float4*)(x + (size_t)b0 * ND);
    #pragma unroll
    for (int k = 0; k < 4; ++k) {
        const int i = tid + k * 1024;       // 4096 float4s
        const float4 vv = xg[i];
        const int bb = i >> 6;
        const int cc = (i & 63) << 2;
        v4f val = { fast_exp2(s * vv.x), fast_exp2(s * vv.y),
                    fast_exp2(s * vv.z), fast_exp2(s * vv.w) };
        *(v4f*)(xs + bb * XS_STRIDE + cc) = val;
    }
    __syncthreads();

    const int lane = tid & 63;
    const int w = tid >> 6;
    const int r = __builtin_amdgcn_readfirstlane(blockIdx.y * 16 + w);

    // Opaque VGPR zero: makes the P address formally lane-dependent so the
    // compiler emits vector global_load_dwordx4 instead of scalarizing to s_load.
    int zr;
    asm("v_mov_b32 %0, 0" : "=v"(zr));

    const float4* __restrict__ pr = P4 + (size_t)r * ND + zr;
    const v4f* xrow4 = (const v4f*)(xs + lane * XS_STRIDE);

    float acc0 = 0.0f, acc1 = 0.0f;

    #pragma unroll 2
    for (int t = 0; t < 64; ++t) {          // 4 elems per iter
        const v4f X4 = xrow4[t];            // ds_read_b128
        const float4 p0 = pr[4 * t + 0];
        const float4 p1 = pr[4 * t + 1];
        const float4 p2 = pr[4 * t + 2];
        const float4 p3 = pr[4 * t + 3];
        elemstep(X4.x, p0, acc0);
        elemstep(X4.y, p1, acc1);
        elemstep(X4.z, p2, acc0);
        elemstep(X4.w, p3, acc1);
    }

    const float ev = baseR[r] - 2.0f * (acc0 + acc1);
    const float za = (kBETA * kLOG2E) * (t_arr[r] - ev);
    const float z = fast_rcp(1.0f + fast_exp2(za));
    const float zw = z * head_w[r];

    // Block-level reduction over the 16 waves (16 r's), then 1 atomic per lane.
    __syncthreads();
    xs[w * 64 + lane] = zw;
    __syncthreads();
    if (w == 0) {
        float ssum = 0.0f;
        #pragma unroll
        for (int q = 0; q < 16; ++q) ssum += xs[q * 64 + lane];
        atomicAdd(&y[b0 + lane], ssum);
    }
}

extern "C" void kernel_launch(void* const* d_in, const int* in_sizes, int n_in,
                              void* d_out, int out_size, void* d_ws, size_t ws_size,
                              hipStream_t stream) {
    const float* x         = (const float*)d_in[0];
    const float* center    = (const float*)d_in[1];
    const float* log_width = (const float*)d_in[2];
    const float* e_low     = (const float*)d_in[3];
    const float* e_high    = (const float*)d_in[4];
    const float* mask      = (const float*)d_in[5];
    const float* log_kappa = (const float*)d_in[6];
    const float* t_arr     = (const float*)d_in[7];
    const float* head_w    = (const float*)d_in[8];
    const float* head_b    = (const float*)d_in[9];
    float* y = (float*)d_out;

    float4* P4   = (float4*)d_ws;                                    // 2 MB
    float* baseR = (float*)((char*)d_ws + sizeof(float4) * NR * ND); // +2 KB

    prep_kernel<<<NR, 256, 0, stream>>>(center, log_width, e_low, e_high,
                                        mask, log_kappa, head_b, P4, baseR, y);
    evid_kernel<<<dim3(NB / 64, NR / 16), 1024, 0, stream>>>(x, log_kappa, t_arr,
                                                             head_w, P4, baseR, y);
}

// Round 6
// 106.602 us; speedup vs baseline: 1.2546x; 1.2546x over previous
//
#include <hip/hip_runtime.h>
#include <math.h>

#define NB 1024
#define NR 512
#define ND 256
#define XS_STRIDE 260   // mult of 4: 16B-aligned rows for ds_read_b128

typedef float v4f __attribute__((ext_vector_type(4)));

constexpr float kBETA  = 6.0f;
constexpr float kLOG2E = 1.4426950408889634f;

#if __has_builtin(__builtin_amdgcn_exp2f)
__device__ __forceinline__ float fast_exp2(float x) { return __builtin_amdgcn_exp2f(x); }
#else
__device__ __forceinline__ float fast_exp2(float x) { return exp2f(x); }
#endif
#if __has_builtin(__builtin_amdgcn_rcpf)
__device__ __forceinline__ float fast_rcp(float x) { return __builtin_amdgcn_rcpf(x); }
#else
__device__ __forceinline__ float fast_rcp(float x) { return 1.0f / x; }
#endif

__device__ __forceinline__ float fast_sigmoid(float a) {   // 1/(1+e^-a)
    return fast_rcp(1.0f + fast_exp2(-a * kLOG2E));
}
__device__ __forceinline__ float fast_tanh(float a) {      // 1 - 2/(1+e^{2a})
    return 1.0f - 2.0f * fast_rcp(1.0f + fast_exp2(a * (2.0f * kLOG2E)));
}

// Prep: P4[r*ND+d] = {E, K, A1, A0} with b = Xe*E (separable exp):
//   E  = exp2(-s*t_high), K = exp2(-s*width)
//   element term (vs baseR): (A1*b + A0) / ((b+1)(b+K))
//   A1 = meh - mel*K, A0 = K*(meh - mel)
// baseR[r] = sum_d (meh - mel); evidence = baseR - 2*sum(term)
__global__ __launch_bounds__(256) void prep_kernel(
    const float* __restrict__ center, const float* __restrict__ log_width,
    const float* __restrict__ e_low, const float* __restrict__ e_high,
    const float* __restrict__ mask, const float* __restrict__ log_kappa,
    const float* __restrict__ head_b,
    float4* __restrict__ P4, float* __restrict__ baseR, float* __restrict__ y)
{
    const int r = blockIdx.x;
    const int d = threadIdx.x;
    const int idx = r * ND + d;

    const float kappa = fminf(fmaxf(fast_exp2(log_kappa[0] * kLOG2E), 0.5f), 50.0f);
    const float s = kappa * kLOG2E;

    const float wdt = fminf(fmaxf(fast_exp2(log_width[idx] * kLOG2E), 0.001f), 50.0f);
    const float th  = center[idx] + 0.5f * wdt;
    const float E   = fast_exp2(-s * th);
    const float K   = fmaxf(fast_exp2(-s * wdt), 1e-30f);   // floor: keeps den > 0
    const float m   = fast_sigmoid(mask[idx]);
    const float mel = m * fast_tanh(e_low[idx]);
    const float meh = m * fast_tanh(e_high[idx]);

    float4 p;
    p.x = E;
    p.y = K;
    p.z = fmaf(-mel, K, meh);      // A1
    p.w = K * (meh - mel);         // A0
    P4[idx] = p;

    float v = meh - mel;
    #pragma unroll
    for (int off = 32; off > 0; off >>= 1) v += __shfl_down(v, off, 64);
    __shared__ float red[4];
    if ((d & 63) == 0) red[d >> 6] = v;
    __syncthreads();
    if (d == 0) baseR[r] = red[0] + red[1] + red[2] + red[3];

    const int gid = blockIdx.x * 256 + threadIdx.x;
    if (gid < NB) y[gid] = head_b[0];
}

// Fused pair: two elements share one division.
//   per elem: b = X*E; q = b+K; den = q*b+q; num = A1*b+A0     (4 VALU)
//   combine:  acc += (num1*den2 + num2*den1) * rcp(den1*den2)  (4 VALU + 1 rcp)
// Xe clamped to 2^+-14 in staging => den <= ~2^21, den1*den2 <= 2^43: no overflow.
__device__ __forceinline__ void pairstep(const float X1, const float X2,
                                         const float4 p1, const float4 p2,
                                         float& acc)
{
    const float b1   = X1 * p1.x;
    const float b2   = X2 * p2.x;
    const float q1   = b1 + p1.y;
    const float q2   = b2 + p2.y;
    const float den1 = fmaf(q1, b1, q1);
    const float den2 = fmaf(q2, b2, q2);
    const float num1 = fmaf(p1.z, b1, p1.w);
    const float num2 = fmaf(p2.z, b2, p2.w);
    const float nn   = fmaf(num2, den1, num1 * den2);
    const float dd   = den1 * den2;
    acc = fmaf(nn, fast_rcp(dd), acc);
}

// Main: 1024 threads = 16 waves; wave w -> r = blockIdx.y*16 + w; lane = b.
// Xe tile in LDS (ds_read_b128); P on the SMEM path (wave-uniform r -> s_load,
// proven best in rounds 3-4; round 5's vector-load detour regressed 1.77x).
__global__ __launch_bounds__(1024, 8) void evid_kernel(
    const float* __restrict__ x, const float* __restrict__ log_kappa,
    const float* __restrict__ t_arr, const float* __restrict__ head_w,
    const float4* __restrict__ P4, const float* __restrict__ baseR,
    float* __restrict__ y)
{
    __shared__ float xs[64 * XS_STRIDE];

    const int tid = threadIdx.x;
    const int b0 = blockIdx.x * 64;

    const float kappa = fminf(fmaxf(fast_exp2(log_kappa[0] * kLOG2E), 0.5f), 50.0f);
    const float s = kappa * kLOG2E;

    // Stage Xe = clamp(exp2(s*x), 2^-14, 2^14): float4 global reads, ds_write_b128.
    const float4* xg = (const float4*)(x + (size_t)b0 * ND);
    #pragma unroll
    for (int k = 0; k < 4; ++k) {
        const int i = tid + k * 1024;       // 4096 float4s
        const float4 vv = xg[i];
        const int bb = i >> 6;
        const int cc = (i & 63) << 2;
        v4f val = { fminf(fmaxf(fast_exp2(s * vv.x), 6.1035156e-5f), 16384.0f),
                    fminf(fmaxf(fast_exp2(s * vv.y), 6.1035156e-5f), 16384.0f),
                    fminf(fmaxf(fast_exp2(s * vv.z), 6.1035156e-5f), 16384.0f),
                    fminf(fmaxf(fast_exp2(s * vv.w), 6.1035156e-5f), 16384.0f) };
        *(v4f*)(xs + bb * XS_STRIDE + cc) = val;
    }
    __syncthreads();

    const int lane = tid & 63;
    const int w = tid >> 6;
    const int r = __builtin_amdgcn_readfirstlane(blockIdx.y * 16 + w);

    const float4* __restrict__ pr = P4 + (size_t)r * ND;   // uniform -> s_load path
    const v4f* xrow4 = (const v4f*)(xs + lane * XS_STRIDE);

    float acc0 = 0.0f, acc1 = 0.0f;

    #pragma unroll 4
    for (int t = 0; t < 64; ++t) {          // 4 elems = 2 fused pairs per iter
        const v4f X4 = xrow4[t];            // ds_read_b128
        const float4 p0 = pr[4 * t + 0];
        const float4 p1 = pr[4 * t + 1];
        const float4 p2 = pr[4 * t + 2];
        const float4 p3 = pr[4 * t + 3];
        pairstep(X4.x, X4.y, p0, p1, acc0);
        pairstep(X4.z, X4.w, p2, p3, acc1);
    }

    const float ev = baseR[r] - 2.0f * (acc0 + acc1);
    const float za = (kBETA * kLOG2E) * (t_arr[r] - ev);
    const float z = fast_rcp(1.0f + fast_exp2(za));
    const float zw = z * head_w[r];

    // Block-level reduction over the 16 waves (16 r's), then 1 atomic per lane.
    __syncthreads();
    xs[w * 64 + lane] = zw;
    __syncthreads();
    if (w == 0) {
        float ssum = 0.0f;
        #pragma unroll
        for (int q = 0; q < 16; ++q) ssum += xs[q * 64 + lane];
        atomicAdd(&y[b0 + lane], ssum);
    }
}

extern "C" void kernel_launch(void* const* d_in, const int* in_sizes, int n_in,
                              void* d_out, int out_size, void* d_ws, size_t ws_size,
                              hipStream_t stream) {
    const float* x         = (const float*)d_in[0];
    const float* center    = (const float*)d_in[1];
    const float* log_width = (const float*)d_in[2];
    const float* e_low     = (const float*)d_in[3];
    const float* e_high    = (const float*)d_in[4];
    const float* mask      = (const float*)d_in[5];
    const float* log_kappa = (const float*)d_in[6];
    const float* t_arr     = (const float*)d_in[7];
    const float* head_w    = (const float*)d_in[8];
    const float* head_b    = (const float*)d_in[9];
    float* y = (float*)d_out;

    float4* P4   = (float4*)d_ws;                                    // 2 MB
    float* baseR = (float*)((char*)d_ws + sizeof(float4) * NR * ND); // +2 KB

    prep_kernel<<<NR, 256, 0, stream>>>(center, log_width, e_low, e_high,
                                        mask, log_kappa, head_b, P4, baseR, y);
    evid_kernel<<<dim3(NB / 64, NR / 16), 1024, 0, stream>>>(x, log_kappa, t_arr,
                                                             head_w, P4, baseR, y);
}